// Round 8
// baseline (30.397 us; speedup 1.0000x reference)
//
#include <hip/hip_runtime.h>

#define LOG2E 1.4426950408889634f
#define C1 (10.0f * LOG2E)

// Single fused kernel. grid 2048 = (b:4, co:32, chunk:16 of 2 output rows).
// 256 threads = 4 waves; wave w owns ci in [4w, 4w+4).
// Math: out = K0 + sum_{ci,j,nb} [ -W2 * sig2 ], sig2 = 1/(1+2^u),
//   u = Zk*x + A - B*cn,  cn = 1/(1+E1*T1),  E1 = 2^(C1*x) staged per pixel,
//   T1=2^(C1*Ec), Zk=2*LOG2E*k, A=Zk*Ec, B=0.2*A, W2=2*Ps*coef,
//   K0 = sum coef*(Ps+bias) + out_bias.
// Both reciprocals batched 3-wide (one v_rcp per nb-group per phase).
__global__ __launch_bounds__(256, 4) void fused_kernel(
    const float* __restrict__ x, const float* __restrict__ kk,
    const float* __restrict__ Ec, const float* __restrict__ Ps,
    const float* __restrict__ bias, const float* __restrict__ coef,
    const float* __restrict__ out_bias, float* __restrict__ out) {
    __shared__ float2 sX[2176];   // [ci:16][r:4][c:34] = (x, E1)
    __shared__ float4 sP[432];    // [ci:16][j:9][nb:3] = {T1, Zk, A, B}
    __shared__ float  sW[432];    // W2
    __shared__ float  red[256];
    __shared__ float  wK0[4];

    const int bid = blockIdx.x, tid = threadIdx.x;
    const int chunk = bid & 15;
    const int co    = (bid >> 4) & 31;
    const int b     = bid >> 9;

    // ---- stage x / E1 slab (rows chunk*2-1 .. chunk*2+2, cols -1..32) ----
    for (int t = tid; t < 2176; t += 256) {
        int ci  = t / 136;
        int rem = t - ci * 136;
        int r   = rem / 34;
        int c   = rem - r * 34;
        int row = chunk * 2 + r - 1;
        int col = c - 1;
        float xv = 0.f;
        if ((unsigned)row < 32u && (unsigned)col < 32u)
            xv = x[((b * 16 + ci) << 10) + (row << 5) + col];
        sX[t] = make_float2(xv, __builtin_amdgcn_exp2f(C1 * xv));
    }

    // ---- derive this co's params; accumulate K0 partial ----
    float kpart = 0.f;
    for (int t = tid; t < 432; t += 256) {
        int ci = t / 27;
        int r2 = t - ci * 27;
        int j  = r2 / 3;
        int nb = r2 - j * 3;
        int i  = co * 432 + ci * 27 + nb * 9 + j;   // input layout [ci][nb][j]
        float e  = Ec[i];
        float zk = 2.0f * LOG2E * kk[i];
        float a  = zk * e;
        float ps = Ps[i], cf = coef[i];
        sP[t] = make_float4(__builtin_amdgcn_exp2f(C1 * e), zk, a, 0.2f * a);
        sW[t] = 2.0f * ps * cf;
        kpart += cf * (ps + bias[i]);
    }
    #pragma unroll
    for (int off = 32; off >= 1; off >>= 1) kpart += __shfl_down(kpart, off, 64);
    if ((tid & 63) == 0) wK0[tid >> 6] = kpart;
    __syncthreads();

    // ---- main compute ----
    const int px = tid & 63;
    const int w  = px & 31;
    const int hr = px >> 5;                 // 0..1
    const int cb = (tid >> 6) << 2;

    float a0 = 0.f, a1 = 0.f, a2 = 0.f;
    #pragma unroll
    for (int i = 0; i < 4; ++i) {
        const float2* xw = &sX[(cb + i) * 136 + hr * 34 + w];
        float2 X[9];
        #pragma unroll
        for (int j = 0; j < 9; ++j)
            X[j] = xw[(j / 3) * 34 + (j % 3)];
        const float4* pc = &sP[(cb + i) * 27];
        const float*  wc = &sW[(cb + i) * 27];
        #pragma unroll
        for (int j = 0; j < 9; ++j) {
            const float xv = X[j].x, E1 = X[j].y;
            const float4 P0 = pc[j * 3 + 0];
            const float4 P1 = pc[j * 3 + 1];
            const float4 P2 = pc[j * 3 + 2];
            const float w0 = wc[j * 3 + 0];
            const float w1 = wc[j * 3 + 1];
            const float w2v = wc[j * 3 + 2];
            // phase 1: cn_i = 1/d_i, one rcp for the 3 nb
            float d0 = fminf(__builtin_fmaf(E1, P0.x, 1.f), 0x1p40f);
            float d1 = fminf(__builtin_fmaf(E1, P1.x, 1.f), 0x1p40f);
            float d2 = fminf(__builtin_fmaf(E1, P2.x, 1.f), 0x1p40f);
            float q01 = d0 * d1, q12 = d1 * d2, q02 = d0 * d2;
            float rp = __builtin_amdgcn_rcpf(q01 * d2);
            float t0 = __builtin_fmaf(P0.y, xv, P0.z);
            float t1 = __builtin_fmaf(P1.y, xv, P1.z);
            float t2 = __builtin_fmaf(P2.y, xv, P2.z);
            float m0 = P0.w * q12, m1 = P1.w * q02, m2 = P2.w * q01;
            float u0 = __builtin_fmaf(-m0, rp, t0);
            float u1 = __builtin_fmaf(-m1, rp, t1);
            float u2 = __builtin_fmaf(-m2, rp, t2);
            // phase 2: r_i = 1/(1+2^u_i), one rcp for the 3 nb
            float e0 = __builtin_amdgcn_exp2f(u0);
            float e1 = __builtin_amdgcn_exp2f(u1);
            float e2 = __builtin_amdgcn_exp2f(u2);
            float f0 = fminf(1.f + e0, 0x1p42f);
            float f1 = fminf(1.f + e1, 0x1p42f);
            float f2 = fminf(1.f + e2, 0x1p42f);
            float s01 = f0 * f1, s12 = f1 * f2, s02 = f0 * f2;
            float rq = __builtin_amdgcn_rcpf(s01 * f2);
            float n0 = w0 * s12, n1 = w1 * s02, n2 = w2v * s01;
            a0 = __builtin_fmaf(-n0, rq, a0);
            a1 = __builtin_fmaf(-n1, rq, a1);
            a2 = __builtin_fmaf(-n2, rq, a2);
        }
    }
    red[tid] = a0 + a1 + a2;
    __syncthreads();
    if (tid < 64) {
        float r = red[tid] + red[tid + 64] + red[tid + 128] + red[tid + 192];
        float k0 = wK0[0] + wK0[1] + wK0[2] + wK0[3] + out_bias[co];
        int o = ((b * 32 + co) << 10) + (chunk << 6) + tid;
        out[o] = r + k0;
    }
}

extern "C" void kernel_launch(void* const* d_in, const int* in_sizes, int n_in,
                              void* d_out, int out_size, void* d_ws, size_t ws_size,
                              hipStream_t stream) {
    const float* x        = (const float*)d_in[0];
    const float* k        = (const float*)d_in[1];
    const float* Ec       = (const float*)d_in[2];
    const float* Ps       = (const float*)d_in[3];
    const float* bias     = (const float*)d_in[4];
    const float* coef     = (const float*)d_in[5];
    const float* out_bias = (const float*)d_in[6];
    float* out = (float*)d_out;

    fused_kernel<<<2048, 256, 0, stream>>>(x, k, Ec, Ps, bias, coef, out_bias, out);
}

// Round 9
// 29.706 us; speedup vs baseline: 1.0232x; 1.0232x over previous
//
#include <hip/hip_runtime.h>

#define LOG2E 1.4426950408889634f
#define C1 (10.0f * LOG2E)

// Single fused kernel. grid 1024 = (b:4, co:32, chunk:8 of 4 output rows).
// 256 threads = 4 waves; wave w owns ci in [4w,4w+4); each lane computes 2 pixels
// (rows chunk*4+hr and chunk*4+hr+2, col w).
// Math per term: cn = 1/(1+E1*T1); u = fma(Zk,x,A) - B*cn; out -= W2/(1+2^u).
// Phase-2 reciprocal batched 3-wide per pixel (one v_rcp per nb-group).
__global__ __launch_bounds__(256, 4) void fused_kernel(
    const float* __restrict__ x, const float* __restrict__ kk,
    const float* __restrict__ Ec, const float* __restrict__ Ps,
    const float* __restrict__ bias, const float* __restrict__ coef,
    const float* __restrict__ out_bias, float* __restrict__ out) {
    __shared__ float2 sX[3264];   // [ci:16][r:6][c:34] = (x, E1=2^(C1 x)), pad->(0,1)
    __shared__ float4 sP[432];    // [ci:16][j:9][nb:3] = {T1, Zk, A, B=0.2A}
    __shared__ float  sW[432];    // W2 = 2*Ps*coef
    __shared__ float  wK0[4];

    const int bid = blockIdx.x, tid = threadIdx.x;
    const int chunk = bid & 7;
    const int co    = (bid >> 3) & 31;
    const int b     = bid >> 8;

    // ---- stage x/E1 slab: padded rows chunk*4-1 .. chunk*4+4, cols -1..32 ----
    for (int t = tid; t < 3264; t += 256) {
        int ci  = t / 204;
        int rem = t - ci * 204;
        int r   = rem / 34;
        int c   = rem - r * 34;
        int row = chunk * 4 + r - 1;
        int col = c - 1;
        float xv = 0.f;
        if ((unsigned)row < 32u && (unsigned)col < 32u)
            xv = x[((b * 16 + ci) << 10) + (row << 5) + col];
        sX[t] = make_float2(xv, __builtin_amdgcn_exp2f(C1 * xv));
    }

    // ---- derive this co's params; K0 partial ----
    float kpart = 0.f;
    for (int t = tid; t < 432; t += 256) {
        int ci = t / 27;
        int r2 = t - ci * 27;
        int j  = r2 / 3;
        int nb = r2 - j * 3;
        int i  = co * 432 + ci * 27 + nb * 9 + j;   // input layout [ci][nb][j]
        float e  = Ec[i];
        float zk = 2.0f * LOG2E * kk[i];
        float a  = zk * e;
        float ps = Ps[i], cf = coef[i];
        sP[t] = make_float4(__builtin_amdgcn_exp2f(C1 * e), zk, a, 0.2f * a);
        sW[t] = 2.0f * ps * cf;
        kpart += cf * (ps + bias[i]);
    }
    #pragma unroll
    for (int off = 32; off >= 1; off >>= 1) kpart += __shfl_down(kpart, off, 64);
    if ((tid & 63) == 0) wK0[tid >> 6] = kpart;
    __syncthreads();

    const int px = tid & 63;
    const int w  = px & 31;
    const int hr = px >> 5;                 // 0..1
    const int cb = (tid >> 6) << 2;

    float a00 = 0.f, a01 = 0.f, a02 = 0.f;  // pixel 0 (row chunk*4+hr)
    float a10 = 0.f, a11 = 0.f, a12 = 0.f;  // pixel 1 (row chunk*4+hr+2)
    #pragma unroll
    for (int i = 0; i < 4; ++i) {
        const int ci = cb + i;
        const float2* xw = &sX[ci * 204 + hr * 34 + w];
        float2 X0[9], X1[9];
        #pragma unroll
        for (int j = 0; j < 9; ++j) {
            X0[j] = xw[(j / 3) * 34 + (j % 3)];
            X1[j] = xw[(j / 3) * 34 + (j % 3) + 68];   // rows +2 (shares row hr+2 loads via CSE)
        }
        const float4* pc = &sP[ci * 27];
        const float*  wc = &sW[ci * 27];
        #pragma unroll
        for (int j = 0; j < 9; ++j) {
            const float4 P0 = pc[j * 3 + 0];
            const float4 P1 = pc[j * 3 + 1];
            const float4 P2 = pc[j * 3 + 2];
            const float w0 = wc[j * 3 + 0];
            const float w1 = wc[j * 3 + 1];
            const float w2v = wc[j * 3 + 2];
            // ---- pixel 0 ----
            {
                const float xv = X0[j].x, E1 = X0[j].y;
                float cn0 = __builtin_amdgcn_rcpf(__builtin_fmaf(E1, P0.x, 1.f));
                float cn1 = __builtin_amdgcn_rcpf(__builtin_fmaf(E1, P1.x, 1.f));
                float cn2 = __builtin_amdgcn_rcpf(__builtin_fmaf(E1, P2.x, 1.f));
                float u0 = __builtin_fmaf(-P0.w, cn0, __builtin_fmaf(P0.y, xv, P0.z));
                float u1 = __builtin_fmaf(-P1.w, cn1, __builtin_fmaf(P1.y, xv, P1.z));
                float u2 = __builtin_fmaf(-P2.w, cn2, __builtin_fmaf(P2.y, xv, P2.z));
                float f0 = fminf(1.f + __builtin_amdgcn_exp2f(u0), 0x1p42f);
                float f1 = fminf(1.f + __builtin_amdgcn_exp2f(u1), 0x1p42f);
                float f2 = fminf(1.f + __builtin_amdgcn_exp2f(u2), 0x1p42f);
                float s01 = f0 * f1, s12 = f1 * f2, s02 = f0 * f2;
                float rq = __builtin_amdgcn_rcpf(s01 * f2);
                a00 = __builtin_fmaf(-(w0 * s12), rq, a00);
                a01 = __builtin_fmaf(-(w1 * s02), rq, a01);
                a02 = __builtin_fmaf(-(w2v * s01), rq, a02);
            }
            // ---- pixel 1 ----
            {
                const float xv = X1[j].x, E1 = X1[j].y;
                float cn0 = __builtin_amdgcn_rcpf(__builtin_fmaf(E1, P0.x, 1.f));
                float cn1 = __builtin_amdgcn_rcpf(__builtin_fmaf(E1, P1.x, 1.f));
                float cn2 = __builtin_amdgcn_rcpf(__builtin_fmaf(E1, P2.x, 1.f));
                float u0 = __builtin_fmaf(-P0.w, cn0, __builtin_fmaf(P0.y, xv, P0.z));
                float u1 = __builtin_fmaf(-P1.w, cn1, __builtin_fmaf(P1.y, xv, P1.z));
                float u2 = __builtin_fmaf(-P2.w, cn2, __builtin_fmaf(P2.y, xv, P2.z));
                float f0 = fminf(1.f + __builtin_amdgcn_exp2f(u0), 0x1p42f);
                float f1 = fminf(1.f + __builtin_amdgcn_exp2f(u1), 0x1p42f);
                float f2 = fminf(1.f + __builtin_amdgcn_exp2f(u2), 0x1p42f);
                float s01 = f0 * f1, s12 = f1 * f2, s02 = f0 * f2;
                float rq = __builtin_amdgcn_rcpf(s01 * f2);
                a10 = __builtin_fmaf(-(w0 * s12), rq, a10);
                a11 = __builtin_fmaf(-(w1 * s02), rq, a11);
                a12 = __builtin_fmaf(-(w2v * s01), rq, a12);
            }
        }
    }

    // ---- cross-wave reduce (reuse sX as scratch) ----
    __syncthreads();
    float* sR = (float*)sX;       // 512 floats needed, 26KB available
    sR[tid]       = a00 + a01 + a02;
    sR[tid + 256] = a10 + a11 + a12;
    __syncthreads();
    if (tid < 64) {
        float r0 = sR[tid] + sR[tid + 64] + sR[tid + 128] + sR[tid + 192];
        float r1 = sR[tid + 256] + sR[tid + 320] + sR[tid + 384] + sR[tid + 448];
        float k0 = wK0[0] + wK0[1] + wK0[2] + wK0[3] + out_bias[co];
        int o0 = ((b * 32 + co) << 10) + ((chunk * 4 + (tid >> 5)) << 5) + (tid & 31);
        out[o0]      = r0 + k0;
        out[o0 + 64] = r1 + k0;   // row +2
    }
}

extern "C" void kernel_launch(void* const* d_in, const int* in_sizes, int n_in,
                              void* d_out, int out_size, void* d_ws, size_t ws_size,
                              hipStream_t stream) {
    const float* x        = (const float*)d_in[0];
    const float* k        = (const float*)d_in[1];
    const float* Ec       = (const float*)d_in[2];
    const float* Ps       = (const float*)d_in[3];
    const float* bias     = (const float*)d_in[4];
    const float* coef     = (const float*)d_in[5];
    const float* out_bias = (const float*)d_in[6];
    float* out = (float*)d_out;

    fused_kernel<<<1024, 256, 0, stream>>>(x, k, Ec, Ps, bias, coef, out_bias, out);
}